// Round 13
// baseline (309.754 us; speedup 1.0000x reference)
//
#include <hip/hip_runtime.h>
#include <hip/hip_bf16.h>

#define N_NODES 50000
#define N_EDGES 600000
#define NMETA   3
#define LTOT (NMETA * N_NODES)          // 150000
#define SPAN_SHIFT 9
#define NBUCK 98                         // ceil(50000 / 512)
#define BCAP 8192
#define NCHUNK 147                       // ceil(600000 / 4096)
#define NABLK 782                        // ceil(50000 / 64)
#define NSLOT (NMETA * NBUCK * BCAP)     // 2408448
#define NSEMBLK ((LTOT / 16 + 3) / 4)    // 2344
#define LOG2E 1.4426950408889634f

typedef unsigned short u16;
typedef short bf16x8 __attribute__((ext_vector_type(8)));
typedef float f32x4 __attribute__((ext_vector_type(4)));

__device__ __forceinline__ float bf2f(u16 v) {
    union { unsigned int u; float f; } x; x.u = ((unsigned int)v) << 16; return x.f;
}
__device__ __forceinline__ float u2f(unsigned int u) {
    union { unsigned int u; float f; } x; x.u = u; return x.f;
}
__device__ __forceinline__ u16 f2bf(float f) {
    return __hip_bfloat16_raw(__float2bfloat16(f)).x;
}

#if __has_builtin(__builtin_amdgcn_fdot2_f32_bf16)
#define HAS_DOT2 1
typedef __bf16 bf16x2v __attribute__((ext_vector_type(2)));
__device__ __forceinline__ float dot2bf(unsigned hp, unsigned ep, float acc) {
    return __builtin_amdgcn_fdot2_f32_bf16(
        __builtin_bit_cast(bf16x2v, hp), __builtin_bit_cast(bf16x2v, ep), acc, false);
}
#else
#define HAS_DOT2 0
#endif

// ---- build1: csrA (0..440) || prep_w (441..696) ----
__global__ __launch_bounds__(256) void k_build1(
    const int* __restrict__ ei, int* __restrict__ gcnt,
    unsigned* __restrict__ pairs,
    const float* __restrict__ W, const float* __restrict__ W1,
    u16* __restrict__ WT, u16* __restrict__ W1T)
{
    const int bid = blockIdx.x;
    const int t = threadIdx.x;
    if (bid >= NMETA * NCHUNK) {
        int idx = (bid - NMETA * NCHUNK) * 256 + t;
        if (idx < NMETA * 16384) {
            int m = idx >> 14, r = idx & 16383;
            int col = r >> 7, k = r & 127;
            WT[idx] = f2bf(W[(m << 14) + k * 128 + col]);
        } else {
            int r = idx - NMETA * 16384;
            int col = r >> 7, k = r & 127;
            W1T[r] = f2bf(W1[k * 128 + col]);
        }
        return;
    }
    const int m = bid / NCHUNK;
    const int e0 = (bid % NCHUNK) * 4096;
    __shared__ int cnt[NBUCK];
    __shared__ int gbase[NBUCK];
    if (t < NBUCK) cnt[t] = 0;
    __syncthreads();
    const int* srcp = ei + (size_t)m * 2 * N_EDGES;
    const int* dstp = srcp + N_EDGES;
    int sa[16], da[16], sl[16];
    #pragma unroll
    for (int j = 0; j < 16; ++j) {
        int e = e0 + j * 256 + t;
        if (e < N_EDGES) {
            int s = srcp[e], d = dstp[e];
            if ((unsigned)s >= N_NODES) s = 0;
            if ((unsigned)d >= N_NODES) d = 0;
            sa[j] = s; da[j] = d;
            sl[j] = atomicAdd(&cnt[d >> SPAN_SHIFT], 1);
        } else sl[j] = -1;
    }
    __syncthreads();
    if (t < NBUCK) gbase[t] = atomicAdd(&gcnt[m * NBUCK + t], cnt[t]);
    __syncthreads();
    #pragma unroll
    for (int j = 0; j < 16; ++j) {
        if (sl[j] < 0) continue;
        int b = da[j] >> SPAN_SHIFT;
        int pos = gbase[b] + sl[j];
        if (pos < BCAP)
            pairs[(size_t)(m * NBUCK + b) * BCAP + pos] =
                ((unsigned)(da[j] & 511) << 23) | (unsigned)(sa[j] * 128);
    }
}

// ---- build2: csrB (0..293) || gemm_h+alpha (rest) ----
__global__ __launch_bounds__(256) void k_build2(
    const int* __restrict__ gcnt, const unsigned* __restrict__ pairs,
    int* __restrict__ row_start, int* __restrict__ row_end, int* __restrict__ eidx,
    int* __restrict__ ptot,
    const float* __restrict__ x, const u16* __restrict__ WT,
    const float* __restrict__ att_src, const float* __restrict__ att_dst,
    u16* __restrict__ h, float* __restrict__ alpha_s, float* __restrict__ alpha_d)
{
    const int bid = blockIdx.x;
    const int t = threadIdx.x;
    if (bid < NMETA * NBUCK) {
        const int m = bid / NBUCK, b = bid % NBUCK;
        __shared__ int cnt[512];
        __shared__ int off[512];
        __shared__ int wsum[4];
        int nb = gcnt[m * NBUCK + b]; if (nb > BCAP) nb = BCAP;
        const int base = (m * NBUCK + b) * BCAP;
        cnt[t] = 0; cnt[t + 256] = 0;
        __syncthreads();
        for (int e = t; e < nb; e += 256) {
            int dl = (int)(pairs[(size_t)base + e] >> 23);
            atomicAdd(&cnt[dl], 1);
        }
        __syncthreads();
        int c0 = cnt[2 * t], c1 = cnt[2 * t + 1];
        int v0p = (c0 + 3) & ~3, v1p = (c1 + 3) & ~3;
        int s = v0p + v1p;
        int lane = t & 63, wv = t >> 6;
        int incl = s;
        #pragma unroll
        for (int o = 1; o < 64; o <<= 1) {
            int u = __shfl_up(incl, o);
            if (lane >= o) incl += u;
        }
        if (lane == 63) wsum[wv] = incl;
        __syncthreads();
        int woff = 0;
        for (int i = 0; i < wv; ++i) woff += wsum[i];
        int ex = woff + incl - s;
        off[2 * t] = ex;
        off[2 * t + 1] = ex + v0p;
        if (t == 255) {
            int tot = ex + v0p + v1p;
            ptot[m * NBUCK + b] = tot < BCAP ? tot : BCAP;
        }
        for (int q = ex + c0; q < ex + v0p && q < BCAP; ++q) eidx[base + q] = 0;
        for (int q = ex + v0p + c1; q < ex + v0p + v1p && q < BCAP; ++q) eidx[base + q] = 0;
        __syncthreads();
        const int node0 = b << SPAN_SHIFT;
        for (int i = t; i < 512; i += 256) {
            int n = node0 + i;
            if (n < N_NODES) {
                int st = base + off[i];
                row_start[m * N_NODES + n] = st;
                row_end[m * N_NODES + n]   = st + cnt[i];
            }
        }
        __syncthreads();
        for (int e = t; e < nb; e += 256) {
            unsigned pv = pairs[(size_t)base + e];
            int dl = (int)(pv >> 23);
            int pos = atomicAdd(&off[dl], 1);
            if (pos >= BCAP) continue;
            eidx[base + pos] = (int)pv;             // packed dl<<23 | src*128
        }
        return;
    }
    // ---- gemm_h + fused alphas (pre-scaled by LOG2E) ----
    const int g = bid - NMETA * NBUCK;
    const int bx = g % NABLK, m = g / NABLK;
    const int wv = t >> 6, lane = t & 63;
    const int row0 = (bx * 4 + wv) * 16;
    if (row0 >= N_NODES) return;
    const int lhi = lane >> 4, llo = lane & 15;
    const float* xrow = x + (size_t)(row0 + llo) * 128 + lhi * 8;
    bf16x8 a[4];
    #pragma unroll
    for (int ks = 0; ks < 4; ++ks) {
        float4 f0 = *(const float4*)(xrow + ks * 32);
        float4 f1 = *(const float4*)(xrow + ks * 32 + 4);
        bf16x8 av;
        av[0] = f2bf(f0.x); av[1] = f2bf(f0.y); av[2] = f2bf(f0.z); av[3] = f2bf(f0.w);
        av[4] = f2bf(f1.x); av[5] = f2bf(f1.y); av[6] = f2bf(f1.z); av[7] = f2bf(f1.w);
        a[ks] = av;
    }
    const u16* wbase = WT + (size_t)m * 16384 + (size_t)llo * 128 + lhi * 8;
    u16* hm = h + ((size_t)m * N_NODES + row0) * 128;
    float sp[4][4], dp[4][4];
    #pragma unroll
    for (int i = 0; i < 4; ++i)
        #pragma unroll
        for (int r = 0; r < 4; ++r) { sp[i][r] = 0.f; dp[i][r] = 0.f; }
    #pragma unroll
    for (int cf = 0; cf < 8; ++cf) {
        f32x4 acc = {0.f, 0.f, 0.f, 0.f};
        const u16* wp = wbase + cf * 16 * 128;
        #pragma unroll
        for (int ks = 0; ks < 4; ++ks) {
            bf16x8 bb = *(const bf16x8*)(wp + ks * 32);
            acc = __builtin_amdgcn_mfma_f32_16x16x32_bf16(a[ks], bb, acc, 0, 0, 0);
        }
        const int col = cf * 16 + llo;
        const int hh = cf >> 1;
        const float as = att_src[m * 128 + col];
        const float adv = att_dst[m * 128 + col];
        #pragma unroll
        for (int r = 0; r < 4; ++r) {
            hm[(size_t)(lhi * 4 + r) * 128 + col] = f2bf(acc[r]);
            sp[hh][r] += acc[r] * as;
            dp[hh][r] += acc[r] * adv;
        }
    }
    #pragma unroll
    for (int o = 1; o <= 8; o <<= 1) {
        #pragma unroll
        for (int i = 0; i < 4; ++i)
            #pragma unroll
            for (int r = 0; r < 4; ++r) {
                sp[i][r] += __shfl_xor(sp[i][r], o);
                dp[i][r] += __shfl_xor(dp[i][r], o);
            }
    }
    if (llo == 0) {
        #pragma unroll
        for (int r = 0; r < 4; ++r) {
            int n = row0 + lhi * 4 + r;
            f32x4 vs = {sp[0][r] * LOG2E, sp[1][r] * LOG2E, sp[2][r] * LOG2E, sp[3][r] * LOG2E};
            f32x4 vd = {dp[0][r] * LOG2E, dp[1][r] * LOG2E, dp[2][r] * LOG2E, dp[3][r] * LOG2E};
            *(f32x4*)(alpha_s + ((size_t)m * N_NODES + n) * 4) = vs;
            *(f32x4*)(alpha_d + ((size_t)m * N_NODES + n) * 4) = vd;
        }
    }
}

// ---- k_ew: grid-stride per-slot edge weights (transposed ew layout); clean eidx ----
__global__ __launch_bounds__(256) void k_ew(
    const int* __restrict__ ptot, int* __restrict__ eidx,
    const float* __restrict__ alpha_s, const float* __restrict__ alpha_d,
    u16* __restrict__ ew)
{
    for (int sidx = blockIdx.x * 256 + threadIdx.x; sidx < NSLOT; sidx += gridDim.x * 256) {
        const int bucket = sidx >> 13;              // / BCAP
        const int i = sidx & (BCAP - 1);
        if (i >= ptot[bucket]) continue;
        const int m = bucket / NBUCK, b = bucket % NBUCK;
        const int node0 = b << SPAN_SHIFT;
        int v = eidx[sidx];
        int src128 = v & 0x7FFFFF;
        int dl = (unsigned)v >> 23;
        const float* as_m = alpha_s + (size_t)m * N_NODES * 4;
        const float* ad_m = alpha_d + (size_t)m * N_NODES * 4;
        f32x4 as4 = *(const f32x4*)(as_m + (src128 >> 5));
        f32x4 ad4 = *(const f32x4*)(ad_m + (size_t)(node0 + dl) * 4);
        u16* ewp = ew + (size_t)(sidx >> 2) * 16 + (sidx & 3);
        #pragma unroll
        for (int k = 0; k < 4; ++k) {
            float pre = as4[k] + ad4[k];
            pre = fmaxf(pre, 0.2f * pre);
            ewp[k * 4] = f2bf(exp2f(pre));
        }
        eidx[sidx] = src128 * 2;                    // byte offset of h row
    }
}

// ---- K2: gather (int4 eidx, packed-bf16 dot2) + softmax + bias + LN + ELU ----
__global__ __launch_bounds__(256) void k_gather(
    const int* __restrict__ row_start, const int* __restrict__ row_end,
    const int* __restrict__ eidx, const u16* __restrict__ ew,
    const float* __restrict__ alpha_s, const float* __restrict__ alpha_d,
    const u16* __restrict__ h,
    const float* __restrict__ bias, const float* __restrict__ gamma,
    const float* __restrict__ lbeta,
    u16* __restrict__ z)                 // [N, M, 128] bf16
{
    long long w = ((long long)blockIdx.x * blockDim.x + threadIdx.x) >> 6;
    if (w >= (long long)LTOT) return;
    int m = (int)(w / N_NODES), n = (int)(w % N_NODES);
    int lane = threadIdx.x & 63, hh = lane >> 4;
    const char* h_m = (const char*)(h + (size_t)m * N_NODES * 128);
    const char* ewb = (const char*)ew;
    const int lb = lane * 4;
    const float* as_m = alpha_s + (size_t)m * N_NODES * 4;
    const float* ad_m = alpha_d + (size_t)m * N_NODES * 4;
    float pre = as_m[n * 4 + hh] + ad_m[n * 4 + hh];
    pre = fmaxf(pre, 0.2f * pre);
    float ev = exp2f(pre);
    float esum = ev;
    unsigned hv = *(const unsigned*)(h_m + (size_t)n * 256 + lb);
    float acc0 = ev * u2f(hv << 16), acc1 = ev * u2f(hv & 0xffff0000u);
    int p = row_start[m * N_NODES + n];            // 4-aligned
    const int end = row_end[m * N_NODES + n];
    for (; p + 3 < end; p += 4) {
        int4 o4 = *(const int4*)(eidx + p);
        uint2 ewv = *(const uint2*)(ewb + (size_t)(p + hh) * 8);
        unsigned h1 = *(const unsigned*)(h_m + o4.x + lb);
        unsigned h2 = *(const unsigned*)(h_m + o4.y + lb);
        unsigned h3 = *(const unsigned*)(h_m + o4.z + lb);
        unsigned h4 = *(const unsigned*)(h_m + o4.w + lb);
#if HAS_DOT2
        unsigned lo12 = __builtin_amdgcn_perm(h2, h1, 0x05040100u);  // {h1.lo, h2.lo}
        unsigned hi12 = __builtin_amdgcn_perm(h2, h1, 0x07060302u);  // {h1.hi, h2.hi}
        unsigned lo34 = __builtin_amdgcn_perm(h4, h3, 0x05040100u);
        unsigned hi34 = __builtin_amdgcn_perm(h4, h3, 0x07060302u);
        acc0 = dot2bf(lo12, ewv.x, acc0);
        acc1 = dot2bf(hi12, ewv.x, acc1);
        acc0 = dot2bf(lo34, ewv.y, acc0);
        acc1 = dot2bf(hi34, ewv.y, acc1);
        esum = dot2bf(0x3F803F80u, ewv.x, esum);   // bf16 {1,1}
        esum = dot2bf(0x3F803F80u, ewv.y, esum);
#else
        float e1 = u2f(ewv.x << 16), e2 = u2f(ewv.x & 0xffff0000u);
        float e3 = u2f(ewv.y << 16), e4 = u2f(ewv.y & 0xffff0000u);
        esum += (e1 + e2) + (e3 + e4);
        acc0 += e1 * u2f(h1 << 16) + e2 * u2f(h2 << 16)
              + e3 * u2f(h3 << 16) + e4 * u2f(h4 << 16);
        acc1 += e1 * u2f(h1 & 0xffff0000u) + e2 * u2f(h2 & 0xffff0000u)
              + e3 * u2f(h3 & 0xffff0000u) + e4 * u2f(h4 & 0xffff0000u);
#endif
    }
    for (; p < end; ++p) {
        int o1 = eidx[p];
        float e1 = bf2f(*(const u16*)(ewb + (size_t)((p & ~3) + hh) * 8 + (p & 3) * 2));
        unsigned h1 = *(const unsigned*)(h_m + o1 + lb);
        esum += e1;
        acc0 += e1 * u2f(h1 << 16);
        acc1 += e1 * u2f(h1 & 0xffff0000u);
    }
    float rinv = 1.f / (esum + 1e-16f);
    float v0 = acc0 * rinv + bias[m * 128 + lane * 2];
    float v1 = acc1 * rinv + bias[m * 128 + lane * 2 + 1];
    float s1 = v0 + v1, s2 = v0 * v0 + v1 * v1;
    #pragma unroll
    for (int o = 32; o >= 1; o >>= 1) { s1 += __shfl_xor(s1, o); s2 += __shfl_xor(s2, o); }
    float mu = s1 * (1.f / 128.f);
    float var = s2 * (1.f / 128.f) - mu * mu;
    float rs = rsqrtf(var + 1e-5f);
    float o0 = (v0 - mu) * rs * gamma[lane * 2]     + lbeta[lane * 2];
    float o1 = (v1 - mu) * rs * gamma[lane * 2 + 1] + lbeta[lane * 2 + 1];
    o0 = o0 > 0.f ? o0 : (__expf(o0) - 1.f);
    o1 = o1 > 0.f ? o1 : (__expf(o1) - 1.f);
    ushort2 outv; outv.x = f2bf(o0); outv.y = f2bf(o1);
    *(ushort2*)(z + ((size_t)n * NMETA + m) * 128 + lane * 2) = outv;
}

// ---- K4: semantic scores via MFMA (+ fused beta via completion counter) ----
__global__ __launch_bounds__(256) void k_sem(
    const u16* __restrict__ z, const u16* __restrict__ W1T,
    const float* __restrict__ b1, const float* __restrict__ W2,
    float* __restrict__ wpart, int* __restrict__ donecnt,
    float* __restrict__ betab, float* __restrict__ attout)
{
    __shared__ float part[NMETA];
    const int t = threadIdx.x;
    if (t < NMETA) part[t] = 0.f;
    __syncthreads();
    const int wv = t >> 6, lane = t & 63;
    const int row0 = (blockIdx.x * 4 + wv) * 16;
    if (row0 < LTOT) {
        const int lhi = lane >> 4, llo = lane & 15;
        const u16* zrow = z + (size_t)(row0 + llo) * 128 + lhi * 8;
        bf16x8 a[4];
        #pragma unroll
        for (int ks = 0; ks < 4; ++ks) a[ks] = *(const bf16x8*)(zrow + ks * 32);
        const u16* wb = W1T + (size_t)llo * 128 + lhi * 8;
        float rowacc[4] = {0.f, 0.f, 0.f, 0.f};
        #pragma unroll
        for (int cf = 0; cf < 8; ++cf) {
            f32x4 acc = {0.f, 0.f, 0.f, 0.f};
            const u16* wp = wb + cf * 16 * 128;
            #pragma unroll
            for (int ks = 0; ks < 4; ++ks) {
                bf16x8 bb = *(const bf16x8*)(wp + ks * 32);
                acc = __builtin_amdgcn_mfma_f32_16x16x32_bf16(a[ks], bb, acc, 0, 0, 0);
            }
            int col = cf * 16 + llo;
            float b1v = b1[col], w2v = W2[col];
            #pragma unroll
            for (int r = 0; r < 4; ++r) {
                float targ = acc[r] + b1v;
                float tv = 1.f - 2.f / (exp2f(targ * (2.f * LOG2E)) + 1.f);  // tanh
                rowacc[r] += tv * w2v;
            }
        }
        #pragma unroll
        for (int o = 1; o <= 8; o <<= 1) {
            #pragma unroll
            for (int r = 0; r < 4; ++r) rowacc[r] += __shfl_xor(rowacc[r], o);
        }
        if (llo == 0) {
            #pragma unroll
            for (int r = 0; r < 4; ++r)
                atomicAdd(&part[(row0 + lhi * 4 + r) % NMETA], rowacc[r]);
        }
    }
    __syncthreads();
    if (t < NMETA) atomicAdd(&wpart[t], part[t]);
    __syncthreads();                                // drain wpart atomics
    if (t == 0) {
        __threadfence();
        int old = atomicAdd(donecnt, 1);
        if (old == NSEMBLK - 1) {                   // last block computes beta
            __threadfence();
            float w0 = wpart[0] * (1.f / N_NODES);
            float w1 = wpart[1] * (1.f / N_NODES);
            float w2 = wpart[2] * (1.f / N_NODES);
            float mx = fmaxf(w0, fmaxf(w1, w2));
            float e0 = __expf(w0 - mx), e1 = __expf(w1 - mx), e2 = __expf(w2 - mx);
            float s = 1.f / (e0 + e1 + e2);
            float b0 = e0 * s, b1v = e1 * s, b2 = e2 * s;
            betab[0] = b0; betab[1] = b1v; betab[2] = b2;
            attout[0] = b0; attout[1] = b1v; attout[2] = b2;
        }
    }
}

// ---- K6: out_emb = sum_m beta[m] * z[:,m,:] (8 cols / thread) ----
__global__ __launch_bounds__(256) void k_combine(
    const u16* __restrict__ z, const float* __restrict__ betab,
    float* __restrict__ out)
{
    int idx = blockIdx.x * blockDim.x + threadIdx.x;   // N*16 tasks
    if (idx >= N_NODES * 16) return;
    int n = idx >> 4, c8 = (idx & 15) * 8;
    float b0 = betab[0], b1 = betab[1], b2 = betab[2];
    const u16* zp = z + (size_t)n * 384 + c8;
    uint4 a0 = *(const uint4*)(zp);
    uint4 a1 = *(const uint4*)(zp + 128);
    uint4 a2 = *(const uint4*)(zp + 256);
    const unsigned* p0 = (const unsigned*)&a0;
    const unsigned* p1 = (const unsigned*)&a1;
    const unsigned* p2 = (const unsigned*)&a2;
    float o[8];
    #pragma unroll
    for (int j = 0; j < 4; ++j) {
        o[2 * j]     = b0 * u2f(p0[j] << 16) + b1 * u2f(p1[j] << 16) + b2 * u2f(p2[j] << 16);
        o[2 * j + 1] = b0 * u2f(p0[j] & 0xffff0000u) + b1 * u2f(p1[j] & 0xffff0000u)
                     + b2 * u2f(p2[j] & 0xffff0000u);
    }
    float* op = out + (size_t)n * 128 + c8;
    *(float4*)(op)     = make_float4(o[0], o[1], o[2], o[3]);
    *(float4*)(op + 4) = make_float4(o[4], o[5], o[6], o[7]);
}

extern "C" void kernel_launch(void* const* d_in, const int* in_sizes, int n_in,
                              void* d_out, int out_size, void* d_ws, size_t ws_size,
                              hipStream_t stream) {
    const float* x       = (const float*)d_in[0];
    const int*   ei      = (const int*)d_in[1];
    const float* W       = (const float*)d_in[2];
    const float* att_src = (const float*)d_in[3];
    const float* att_dst = (const float*)d_in[4];
    const float* bias    = (const float*)d_in[5];
    const float* gamma   = (const float*)d_in[6];
    const float* lbeta   = (const float*)d_in[7];
    const float* W1      = (const float*)d_in[8];
    const float* b1      = (const float*)d_in[9];
    const float* W2      = (const float*)d_in[10];

    char* ws = (char*)d_ws;
    size_t off = 0;
    int* gcnt    = (int*)(ws + off);  off += sizeof(int) * 512;
    int* ptot    = (int*)(ws + off);  off += sizeof(int) * 512;
    float* wpart = (float*)(ws + off);
    float* betab = wpart + 8;
    int* donecnt = (int*)(betab + 8); off += 128;
    const size_t zero_bytes = off;
    off = (off + 255) & ~(size_t)255;
    int* row_start = (int*)(ws + off); off += sizeof(int) * 150016;
    int* row_end   = (int*)(ws + off); off += sizeof(int) * 150016;
    u16* h      = (u16*)(ws + off);    off += sizeof(u16) * (size_t)NMETA * N_NODES * 128;
    float* alpha_s = (float*)(ws + off); off += sizeof(float) * (size_t)LTOT * 4;
    float* alpha_d = (float*)(ws + off); off += sizeof(float) * (size_t)LTOT * 4;
    u16* WT     = (u16*)(ws + off);    off += sizeof(u16) * (size_t)NMETA * 128 * 128;
    u16* W1T    = (u16*)(ws + off);    off += sizeof(u16) * (size_t)128 * 128;
    int* eidx   = (int*)(ws + off);    off += sizeof(int) * (size_t)NSLOT;          // 9.6 MB
    u16* ew     = (u16*)(ws + off);    off += sizeof(u16) * (size_t)NSLOT * 4;      // 19.3 MB
    // union region (disjoint lifetimes): pairs (build1->build2, 9.6 MB), z (gather->end)
    unsigned* pairs = (unsigned*)(ws + off);
    u16* z = (u16*)(ws + off);
    off += sizeof(u16) * (size_t)N_NODES * NMETA * 128;                  // 38.4 MB
    if (ws_size < off) return;  // ~112 MB needed; loud failure if undersized

    hipMemsetAsync(d_ws, 0, zero_bytes, stream);

    // build1: csrA (441) || prep_w (256)
    k_build1<<<dim3(NMETA * NCHUNK + 256), 256, 0, stream>>>(ei, gcnt, pairs, W, W1, WT, W1T);
    // build2: csrB (294) || gemm_h+alpha (2346)
    k_build2<<<dim3(NMETA * NBUCK + NABLK * NMETA), 256, 0, stream>>>(
        gcnt, pairs, row_start, row_end, eidx, ptot,
        x, WT, att_src, att_dst, h, alpha_s, alpha_d);
    k_ew<<<dim3(2048), 256, 0, stream>>>(ptot, eidx, alpha_s, alpha_d, ew);
    k_gather<<<dim3((LTOT + 3) / 4), 256, 0, stream>>>(row_start, row_end, eidx, ew,
                                                       alpha_s, alpha_d, h,
                                                       bias, gamma, lbeta, z);
    k_sem<<<dim3(NSEMBLK), 256, 0, stream>>>(z, W1T, b1, W2, wpart, donecnt,
                                             betab, (float*)d_out + (size_t)N_NODES * 128);
    k_combine<<<dim3((N_NODES * 16 + 255) / 256), 256, 0, stream>>>(z, betab, (float*)d_out);
}

// Round 14
// 262.835 us; speedup vs baseline: 1.1785x; 1.1785x over previous
//
#include <hip/hip_runtime.h>
#include <hip/hip_bf16.h>

#define N_NODES 50000
#define N_EDGES 600000
#define NMETA   3
#define LTOT (NMETA * N_NODES)          // 150000
#define SPAN_SHIFT 9
#define NBUCK 98                         // ceil(50000 / 512)
#define BCAP 8192
#define NCHUNK 147                       // ceil(600000 / 4096)
#define NABLK 782                        // ceil(50000 / 64)
#define NSLOT (NMETA * NBUCK * BCAP)     // 2408448
#define NSEMBLK ((LTOT / 16 + 3) / 4)    // 2344
#define LOG2E 1.4426950408889634f

typedef unsigned short u16;
typedef short bf16x8 __attribute__((ext_vector_type(8)));
typedef float f32x4 __attribute__((ext_vector_type(4)));

__device__ __forceinline__ float bf2f(u16 v) {
    union { unsigned int u; float f; } x; x.u = ((unsigned int)v) << 16; return x.f;
}
__device__ __forceinline__ float u2f(unsigned int u) {
    union { unsigned int u; float f; } x; x.u = u; return x.f;
}
__device__ __forceinline__ u16 f2bf(float f) {
    return __hip_bfloat16_raw(__float2bfloat16(f)).x;
}

#if __has_builtin(__builtin_amdgcn_fdot2_f32_bf16)
#define HAS_DOT2 1
typedef __bf16 bf16x2v __attribute__((ext_vector_type(2)));
__device__ __forceinline__ float dot2bf(unsigned hp, unsigned ep, float acc) {
    return __builtin_amdgcn_fdot2_f32_bf16(
        __builtin_bit_cast(bf16x2v, hp), __builtin_bit_cast(bf16x2v, ep), acc, false);
}
#else
#define HAS_DOT2 0
#endif

// ---- build1: csrA (0..440) || prep_w (441..696) ----
// gcnt is PADDED: one 64B cache line per bucket (index bucket*16) to avoid
// cross-XCD same-line atomic serialization.
__global__ __launch_bounds__(256) void k_build1(
    const int* __restrict__ ei, int* __restrict__ gcnt,
    unsigned* __restrict__ pairs,
    const float* __restrict__ W, const float* __restrict__ W1,
    u16* __restrict__ WT, u16* __restrict__ W1T)
{
    const int bid = blockIdx.x;
    const int t = threadIdx.x;
    if (bid >= NMETA * NCHUNK) {
        int idx = (bid - NMETA * NCHUNK) * 256 + t;
        if (idx < NMETA * 16384) {
            int m = idx >> 14, r = idx & 16383;
            int col = r >> 7, k = r & 127;
            WT[idx] = f2bf(W[(m << 14) + k * 128 + col]);
        } else {
            int r = idx - NMETA * 16384;
            int col = r >> 7, k = r & 127;
            W1T[r] = f2bf(W1[k * 128 + col]);
        }
        return;
    }
    const int m = bid / NCHUNK;
    const int e0 = (bid % NCHUNK) * 4096;
    __shared__ int cnt[NBUCK];
    __shared__ int gbase[NBUCK];
    if (t < NBUCK) cnt[t] = 0;
    __syncthreads();
    const int* srcp = ei + (size_t)m * 2 * N_EDGES;
    const int* dstp = srcp + N_EDGES;
    int sa[16], da[16], sl[16];
    #pragma unroll
    for (int j = 0; j < 16; ++j) {
        int e = e0 + j * 256 + t;
        if (e < N_EDGES) {
            int s = srcp[e], d = dstp[e];
            if ((unsigned)s >= N_NODES) s = 0;
            if ((unsigned)d >= N_NODES) d = 0;
            sa[j] = s; da[j] = d;
            sl[j] = atomicAdd(&cnt[d >> SPAN_SHIFT], 1);
        } else sl[j] = -1;
    }
    __syncthreads();
    if (t < NBUCK) gbase[t] = atomicAdd(&gcnt[(m * NBUCK + t) * 16], cnt[t]);
    __syncthreads();
    #pragma unroll
    for (int j = 0; j < 16; ++j) {
        if (sl[j] < 0) continue;
        int b = da[j] >> SPAN_SHIFT;
        int pos = gbase[b] + sl[j];
        if (pos < BCAP)
            pairs[(size_t)(m * NBUCK + b) * BCAP + pos] =
                ((unsigned)(da[j] & 511) << 23) | (unsigned)(sa[j] * 128);
    }
}

// ---- build2: csrB (0..293) || gemm_h+alpha (rest) ----
__global__ __launch_bounds__(256) void k_build2(
    const int* __restrict__ gcnt, const unsigned* __restrict__ pairs,
    int* __restrict__ row_start, int* __restrict__ row_end, int* __restrict__ eidx,
    int* __restrict__ ptot,
    const float* __restrict__ x, const u16* __restrict__ WT,
    const float* __restrict__ att_src, const float* __restrict__ att_dst,
    u16* __restrict__ h, float* __restrict__ alpha_s, float* __restrict__ alpha_d)
{
    const int bid = blockIdx.x;
    const int t = threadIdx.x;
    if (bid < NMETA * NBUCK) {
        const int m = bid / NBUCK, b = bid % NBUCK;
        __shared__ int cnt[512];
        __shared__ int off[512];
        __shared__ int wsum[4];
        int nb = gcnt[(m * NBUCK + b) * 16]; if (nb > BCAP) nb = BCAP;
        const int base = (m * NBUCK + b) * BCAP;
        cnt[t] = 0; cnt[t + 256] = 0;
        __syncthreads();
        for (int e = t; e < nb; e += 256) {
            int dl = (int)(pairs[(size_t)base + e] >> 23);
            atomicAdd(&cnt[dl], 1);
        }
        __syncthreads();
        int c0 = cnt[2 * t], c1 = cnt[2 * t + 1];
        int v0p = (c0 + 3) & ~3, v1p = (c1 + 3) & ~3;
        int s = v0p + v1p;
        int lane = t & 63, wv = t >> 6;
        int incl = s;
        #pragma unroll
        for (int o = 1; o < 64; o <<= 1) {
            int u = __shfl_up(incl, o);
            if (lane >= o) incl += u;
        }
        if (lane == 63) wsum[wv] = incl;
        __syncthreads();
        int woff = 0;
        for (int i = 0; i < wv; ++i) woff += wsum[i];
        int ex = woff + incl - s;
        off[2 * t] = ex;
        off[2 * t + 1] = ex + v0p;
        if (t == 255) {
            int tot = ex + v0p + v1p;
            ptot[m * NBUCK + b] = tot < BCAP ? tot : BCAP;
        }
        for (int q = ex + c0; q < ex + v0p && q < BCAP; ++q) eidx[base + q] = 0;
        for (int q = ex + v0p + c1; q < ex + v0p + v1p && q < BCAP; ++q) eidx[base + q] = 0;
        __syncthreads();
        const int node0 = b << SPAN_SHIFT;
        for (int i = t; i < 512; i += 256) {
            int n = node0 + i;
            if (n < N_NODES) {
                int st = base + off[i];
                row_start[m * N_NODES + n] = st;
                row_end[m * N_NODES + n]   = st + cnt[i];
            }
        }
        __syncthreads();
        for (int e = t; e < nb; e += 256) {
            unsigned pv = pairs[(size_t)base + e];
            int dl = (int)(pv >> 23);
            int pos = atomicAdd(&off[dl], 1);
            if (pos >= BCAP) continue;
            eidx[base + pos] = (int)pv;             // packed dl<<23 | src*128
        }
        return;
    }
    // ---- gemm_h + fused alphas (pre-scaled by LOG2E) ----
    const int g = bid - NMETA * NBUCK;
    const int bx = g % NABLK, m = g / NABLK;
    const int wv = t >> 6, lane = t & 63;
    const int row0 = (bx * 4 + wv) * 16;
    if (row0 >= N_NODES) return;
    const int lhi = lane >> 4, llo = lane & 15;
    const float* xrow = x + (size_t)(row0 + llo) * 128 + lhi * 8;
    bf16x8 a[4];
    #pragma unroll
    for (int ks = 0; ks < 4; ++ks) {
        float4 f0 = *(const float4*)(xrow + ks * 32);
        float4 f1 = *(const float4*)(xrow + ks * 32 + 4);
        bf16x8 av;
        av[0] = f2bf(f0.x); av[1] = f2bf(f0.y); av[2] = f2bf(f0.z); av[3] = f2bf(f0.w);
        av[4] = f2bf(f1.x); av[5] = f2bf(f1.y); av[6] = f2bf(f1.z); av[7] = f2bf(f1.w);
        a[ks] = av;
    }
    const u16* wbase = WT + (size_t)m * 16384 + (size_t)llo * 128 + lhi * 8;
    u16* hm = h + ((size_t)m * N_NODES + row0) * 128;
    float sp[4][4], dp[4][4];
    #pragma unroll
    for (int i = 0; i < 4; ++i)
        #pragma unroll
        for (int r = 0; r < 4; ++r) { sp[i][r] = 0.f; dp[i][r] = 0.f; }
    #pragma unroll
    for (int cf = 0; cf < 8; ++cf) {
        f32x4 acc = {0.f, 0.f, 0.f, 0.f};
        const u16* wp = wbase + cf * 16 * 128;
        #pragma unroll
        for (int ks = 0; ks < 4; ++ks) {
            bf16x8 bb = *(const bf16x8*)(wp + ks * 32);
            acc = __builtin_amdgcn_mfma_f32_16x16x32_bf16(a[ks], bb, acc, 0, 0, 0);
        }
        const int col = cf * 16 + llo;
        const int hh = cf >> 1;
        const float as = att_src[m * 128 + col];
        const float adv = att_dst[m * 128 + col];
        #pragma unroll
        for (int r = 0; r < 4; ++r) {
            hm[(size_t)(lhi * 4 + r) * 128 + col] = f2bf(acc[r]);
            sp[hh][r] += acc[r] * as;
            dp[hh][r] += acc[r] * adv;
        }
    }
    #pragma unroll
    for (int o = 1; o <= 8; o <<= 1) {
        #pragma unroll
        for (int i = 0; i < 4; ++i)
            #pragma unroll
            for (int r = 0; r < 4; ++r) {
                sp[i][r] += __shfl_xor(sp[i][r], o);
                dp[i][r] += __shfl_xor(dp[i][r], o);
            }
    }
    if (llo == 0) {
        #pragma unroll
        for (int r = 0; r < 4; ++r) {
            int n = row0 + lhi * 4 + r;
            f32x4 vs = {sp[0][r] * LOG2E, sp[1][r] * LOG2E, sp[2][r] * LOG2E, sp[3][r] * LOG2E};
            f32x4 vd = {dp[0][r] * LOG2E, dp[1][r] * LOG2E, dp[2][r] * LOG2E, dp[3][r] * LOG2E};
            *(f32x4*)(alpha_s + ((size_t)m * N_NODES + n) * 4) = vs;
            *(f32x4*)(alpha_d + ((size_t)m * N_NODES + n) * 4) = vd;
        }
    }
}

// ---- k_ew: grid-stride per-slot edge weights (transposed ew layout); clean eidx ----
__global__ __launch_bounds__(256) void k_ew(
    const int* __restrict__ ptot, int* __restrict__ eidx,
    const float* __restrict__ alpha_s, const float* __restrict__ alpha_d,
    u16* __restrict__ ew)
{
    for (int sidx = blockIdx.x * 256 + threadIdx.x; sidx < NSLOT; sidx += gridDim.x * 256) {
        const int bucket = sidx >> 13;              // / BCAP
        const int i = sidx & (BCAP - 1);
        if (i >= ptot[bucket]) continue;
        const int m = bucket / NBUCK, b = bucket % NBUCK;
        const int node0 = b << SPAN_SHIFT;
        int v = eidx[sidx];
        int src128 = v & 0x7FFFFF;
        int dl = (unsigned)v >> 23;
        const float* as_m = alpha_s + (size_t)m * N_NODES * 4;
        const float* ad_m = alpha_d + (size_t)m * N_NODES * 4;
        f32x4 as4 = *(const f32x4*)(as_m + (src128 >> 5));
        f32x4 ad4 = *(const f32x4*)(ad_m + (size_t)(node0 + dl) * 4);
        u16* ewp = ew + (size_t)(sidx >> 2) * 16 + (sidx & 3);
        #pragma unroll
        for (int k = 0; k < 4; ++k) {
            float pre = as4[k] + ad4[k];
            pre = fmaxf(pre, 0.2f * pre);
            ewp[k * 4] = f2bf(exp2f(pre));
        }
        eidx[sidx] = src128 * 2;                    // byte offset of h row
    }
}

// ---- K2: gather (int4 eidx, packed-bf16 dot2) + softmax + bias + LN + ELU ----
__global__ __launch_bounds__(256) void k_gather(
    const int* __restrict__ row_start, const int* __restrict__ row_end,
    const int* __restrict__ eidx, const u16* __restrict__ ew,
    const float* __restrict__ alpha_s, const float* __restrict__ alpha_d,
    const u16* __restrict__ h,
    const float* __restrict__ bias, const float* __restrict__ gamma,
    const float* __restrict__ lbeta,
    u16* __restrict__ z)                 // [N, M, 128] bf16
{
    long long w = ((long long)blockIdx.x * blockDim.x + threadIdx.x) >> 6;
    if (w >= (long long)LTOT) return;
    int m = (int)(w / N_NODES), n = (int)(w % N_NODES);
    int lane = threadIdx.x & 63, hh = lane >> 4;
    const char* h_m = (const char*)(h + (size_t)m * N_NODES * 128);
    const char* ewb = (const char*)ew;
    const int lb = lane * 4;
    const float* as_m = alpha_s + (size_t)m * N_NODES * 4;
    const float* ad_m = alpha_d + (size_t)m * N_NODES * 4;
    float pre = as_m[n * 4 + hh] + ad_m[n * 4 + hh];
    pre = fmaxf(pre, 0.2f * pre);
    float ev = exp2f(pre);
    float esum = ev;
    unsigned hv = *(const unsigned*)(h_m + (size_t)n * 256 + lb);
    float acc0 = ev * u2f(hv << 16), acc1 = ev * u2f(hv & 0xffff0000u);
    int p = row_start[m * N_NODES + n];            // 4-aligned
    const int end = row_end[m * N_NODES + n];
    for (; p + 3 < end; p += 4) {
        int4 o4 = *(const int4*)(eidx + p);
        uint2 ewv = *(const uint2*)(ewb + (size_t)(p + hh) * 8);
        unsigned h1 = *(const unsigned*)(h_m + o4.x + lb);
        unsigned h2 = *(const unsigned*)(h_m + o4.y + lb);
        unsigned h3 = *(const unsigned*)(h_m + o4.z + lb);
        unsigned h4 = *(const unsigned*)(h_m + o4.w + lb);
#if HAS_DOT2
        unsigned lo12 = __builtin_amdgcn_perm(h2, h1, 0x05040100u);  // {h1.lo, h2.lo}
        unsigned hi12 = __builtin_amdgcn_perm(h2, h1, 0x07060302u);  // {h1.hi, h2.hi}
        unsigned lo34 = __builtin_amdgcn_perm(h4, h3, 0x05040100u);
        unsigned hi34 = __builtin_amdgcn_perm(h4, h3, 0x07060302u);
        acc0 = dot2bf(lo12, ewv.x, acc0);
        acc1 = dot2bf(hi12, ewv.x, acc1);
        acc0 = dot2bf(lo34, ewv.y, acc0);
        acc1 = dot2bf(hi34, ewv.y, acc1);
        esum = dot2bf(0x3F803F80u, ewv.x, esum);   // bf16 {1,1}
        esum = dot2bf(0x3F803F80u, ewv.y, esum);
#else
        float e1 = u2f(ewv.x << 16), e2 = u2f(ewv.x & 0xffff0000u);
        float e3 = u2f(ewv.y << 16), e4 = u2f(ewv.y & 0xffff0000u);
        esum += (e1 + e2) + (e3 + e4);
        acc0 += e1 * u2f(h1 << 16) + e2 * u2f(h2 << 16)
              + e3 * u2f(h3 << 16) + e4 * u2f(h4 << 16);
        acc1 += e1 * u2f(h1 & 0xffff0000u) + e2 * u2f(h2 & 0xffff0000u)
              + e3 * u2f(h3 & 0xffff0000u) + e4 * u2f(h4 & 0xffff0000u);
#endif
    }
    for (; p < end; ++p) {
        int o1 = eidx[p];
        float e1 = bf2f(*(const u16*)(ewb + (size_t)((p & ~3) + hh) * 8 + (p & 3) * 2));
        unsigned h1 = *(const unsigned*)(h_m + o1 + lb);
        esum += e1;
        acc0 += e1 * u2f(h1 << 16);
        acc1 += e1 * u2f(h1 & 0xffff0000u);
    }
    float rinv = 1.f / (esum + 1e-16f);
    float v0 = acc0 * rinv + bias[m * 128 + lane * 2];
    float v1 = acc1 * rinv + bias[m * 128 + lane * 2 + 1];
    float s1 = v0 + v1, s2 = v0 * v0 + v1 * v1;
    #pragma unroll
    for (int o = 32; o >= 1; o >>= 1) { s1 += __shfl_xor(s1, o); s2 += __shfl_xor(s2, o); }
    float mu = s1 * (1.f / 128.f);
    float var = s2 * (1.f / 128.f) - mu * mu;
    float rs = rsqrtf(var + 1e-5f);
    float o0 = (v0 - mu) * rs * gamma[lane * 2]     + lbeta[lane * 2];
    float o1 = (v1 - mu) * rs * gamma[lane * 2 + 1] + lbeta[lane * 2 + 1];
    o0 = o0 > 0.f ? o0 : (__expf(o0) - 1.f);
    o1 = o1 > 0.f ? o1 : (__expf(o1) - 1.f);
    ushort2 outv; outv.x = f2bf(o0); outv.y = f2bf(o1);
    *(ushort2*)(z + ((size_t)n * NMETA + m) * 128 + lane * 2) = outv;
}

// ---- K4: semantic scores via MFMA; per-block partial -> OWN cache line (no atomics) ----
__global__ __launch_bounds__(256) void k_sem(
    const u16* __restrict__ z, const u16* __restrict__ W1T,
    const float* __restrict__ b1, const float* __restrict__ W2,
    float4* __restrict__ partial)
{
    __shared__ float part[NMETA];
    const int t = threadIdx.x;
    if (t < NMETA) part[t] = 0.f;
    __syncthreads();
    const int wv = t >> 6, lane = t & 63;
    const int row0 = (blockIdx.x * 4 + wv) * 16;
    if (row0 < LTOT) {
        const int lhi = lane >> 4, llo = lane & 15;
        const u16* zrow = z + (size_t)(row0 + llo) * 128 + lhi * 8;
        bf16x8 a[4];
        #pragma unroll
        for (int ks = 0; ks < 4; ++ks) a[ks] = *(const bf16x8*)(zrow + ks * 32);
        const u16* wb = W1T + (size_t)llo * 128 + lhi * 8;
        float rowacc[4] = {0.f, 0.f, 0.f, 0.f};
        #pragma unroll
        for (int cf = 0; cf < 8; ++cf) {
            f32x4 acc = {0.f, 0.f, 0.f, 0.f};
            const u16* wp = wb + cf * 16 * 128;
            #pragma unroll
            for (int ks = 0; ks < 4; ++ks) {
                bf16x8 bb = *(const bf16x8*)(wp + ks * 32);
                acc = __builtin_amdgcn_mfma_f32_16x16x32_bf16(a[ks], bb, acc, 0, 0, 0);
            }
            int col = cf * 16 + llo;
            float b1v = b1[col], w2v = W2[col];
            #pragma unroll
            for (int r = 0; r < 4; ++r) {
                float targ = acc[r] + b1v;
                float tv = 1.f - 2.f / (exp2f(targ * (2.f * LOG2E)) + 1.f);  // tanh
                rowacc[r] += tv * w2v;
            }
        }
        #pragma unroll
        for (int o = 1; o <= 8; o <<= 1) {
            #pragma unroll
            for (int r = 0; r < 4; ++r) rowacc[r] += __shfl_xor(rowacc[r], o);
        }
        if (llo == 0) {
            #pragma unroll
            for (int r = 0; r < 4; ++r)
                atomicAdd(&part[(row0 + lhi * 4 + r) % NMETA], rowacc[r]);
        }
    }
    __syncthreads();
    if (t == 0)
        partial[blockIdx.x] = make_float4(part[0], part[1], part[2], 0.f);
}

// ---- K5: reduce partials + softmax; write betab + att_mp ----
__global__ __launch_bounds__(256) void k_beta(
    const float4* __restrict__ partial, float* __restrict__ betab,
    float* __restrict__ attout)
{
    const int t = threadIdx.x;
    float s0 = 0.f, s1 = 0.f, s2 = 0.f;
    for (int i = t; i < NSEMBLK; i += 256) {
        float4 v = partial[i];
        s0 += v.x; s1 += v.y; s2 += v.z;
    }
    #pragma unroll
    for (int o = 32; o >= 1; o >>= 1) {
        s0 += __shfl_xor(s0, o);
        s1 += __shfl_xor(s1, o);
        s2 += __shfl_xor(s2, o);
    }
    __shared__ float wsum[3][4];
    int lane = t & 63, wv = t >> 6;
    if (lane == 0) { wsum[0][wv] = s0; wsum[1][wv] = s1; wsum[2][wv] = s2; }
    __syncthreads();
    if (t == 0) {
        float w0 = (wsum[0][0] + wsum[0][1] + wsum[0][2] + wsum[0][3]) * (1.f / N_NODES);
        float w1 = (wsum[1][0] + wsum[1][1] + wsum[1][2] + wsum[1][3]) * (1.f / N_NODES);
        float w2 = (wsum[2][0] + wsum[2][1] + wsum[2][2] + wsum[2][3]) * (1.f / N_NODES);
        float mx = fmaxf(w0, fmaxf(w1, w2));
        float e0 = __expf(w0 - mx), e1 = __expf(w1 - mx), e2 = __expf(w2 - mx);
        float s = 1.f / (e0 + e1 + e2);
        float b0 = e0 * s, b1v = e1 * s, b2 = e2 * s;
        betab[0] = b0; betab[1] = b1v; betab[2] = b2;
        attout[0] = b0; attout[1] = b1v; attout[2] = b2;
    }
}

// ---- K6: out_emb = sum_m beta[m] * z[:,m,:] (8 cols / thread) ----
__global__ __launch_bounds__(256) void k_combine(
    const u16* __restrict__ z, const float* __restrict__ betab,
    float* __restrict__ out)
{
    int idx = blockIdx.x * blockDim.x + threadIdx.x;   // N*16 tasks
    if (idx >= N_NODES * 16) return;
    int n = idx >> 4, c8 = (idx & 15) * 8;
    float b0 = betab[0], b1 = betab[1], b2 = betab[2];
    const u16* zp = z + (size_t)n * 384 + c8;
    uint4 a0 = *(const uint4*)(zp);
    uint4 a1 = *(const uint4*)(zp + 128);
    uint4 a2 = *(const uint4*)(zp + 256);
    const unsigned* p0 = (const unsigned*)&a0;
    const unsigned* p1 = (const unsigned*)&a1;
    const unsigned* p2 = (const unsigned*)&a2;
    float o[8];
    #pragma unroll
    for (int j = 0; j < 4; ++j) {
        o[2 * j]     = b0 * u2f(p0[j] << 16) + b1 * u2f(p1[j] << 16) + b2 * u2f(p2[j] << 16);
        o[2 * j + 1] = b0 * u2f(p0[j] & 0xffff0000u) + b1 * u2f(p1[j] & 0xffff0000u)
                     + b2 * u2f(p2[j] & 0xffff0000u);
    }
    float* op = out + (size_t)n * 128 + c8;
    *(float4*)(op)     = make_float4(o[0], o[1], o[2], o[3]);
    *(float4*)(op + 4) = make_float4(o[4], o[5], o[6], o[7]);
}

extern "C" void kernel_launch(void* const* d_in, const int* in_sizes, int n_in,
                              void* d_out, int out_size, void* d_ws, size_t ws_size,
                              hipStream_t stream) {
    const float* x       = (const float*)d_in[0];
    const int*   ei      = (const int*)d_in[1];
    const float* W       = (const float*)d_in[2];
    const float* att_src = (const float*)d_in[3];
    const float* att_dst = (const float*)d_in[4];
    const float* bias    = (const float*)d_in[5];
    const float* gamma   = (const float*)d_in[6];
    const float* lbeta   = (const float*)d_in[7];
    const float* W1      = (const float*)d_in[8];
    const float* b1      = (const float*)d_in[9];
    const float* W2      = (const float*)d_in[10];

    char* ws = (char*)d_ws;
    size_t off = 0;
    int* gcnt    = (int*)(ws + off);  off += sizeof(int) * 512 * 16;     // padded: 1 line / bucket
    int* ptot    = (int*)(ws + off);  off += sizeof(int) * 512;
    float* betab = (float*)(ws + off); off += 64;
    const size_t zero_bytes = off;
    off = (off + 255) & ~(size_t)255;
    float4* partial = (float4*)(ws + off); off += sizeof(float4) * (NSEMBLK + 8);
    int* row_start = (int*)(ws + off); off += sizeof(int) * 150016;
    int* row_end   = (int*)(ws + off); off += sizeof(int) * 150016;
    u16* h      = (u16*)(ws + off);    off += sizeof(u16) * (size_t)NMETA * N_NODES * 128;
    float* alpha_s = (float*)(ws + off); off += sizeof(float) * (size_t)LTOT * 4;
    float* alpha_d = (float*)(ws + off); off += sizeof(float) * (size_t)LTOT * 4;
    u16* WT     = (u16*)(ws + off);    off += sizeof(u16) * (size_t)NMETA * 128 * 128;
    u16* W1T    = (u16*)(ws + off);    off += sizeof(u16) * (size_t)128 * 128;
    int* eidx   = (int*)(ws + off);    off += sizeof(int) * (size_t)NSLOT;          // 9.6 MB
    u16* ew     = (u16*)(ws + off);    off += sizeof(u16) * (size_t)NSLOT * 4;      // 19.3 MB
    // union region (disjoint lifetimes): pairs (build1->build2, 9.6 MB), z (gather->end)
    unsigned* pairs = (unsigned*)(ws + off);
    u16* z = (u16*)(ws + off);
    off += sizeof(u16) * (size_t)N_NODES * NMETA * 128;                  // 38.4 MB
    if (ws_size < off) return;  // ~112 MB needed; loud failure if undersized

    hipMemsetAsync(d_ws, 0, zero_bytes, stream);

    // build1: csrA (441) || prep_w (256)
    k_build1<<<dim3(NMETA * NCHUNK + 256), 256, 0, stream>>>(ei, gcnt, pairs, W, W1, WT, W1T);
    // build2: csrB (294) || gemm_h+alpha (2346)
    k_build2<<<dim3(NMETA * NBUCK + NABLK * NMETA), 256, 0, stream>>>(
        gcnt, pairs, row_start, row_end, eidx, ptot,
        x, WT, att_src, att_dst, h, alpha_s, alpha_d);
    k_ew<<<dim3(2048), 256, 0, stream>>>(ptot, eidx, alpha_s, alpha_d, ew);
    k_gather<<<dim3((LTOT + 3) / 4), 256, 0, stream>>>(row_start, row_end, eidx, ew,
                                                       alpha_s, alpha_d, h,
                                                       bias, gamma, lbeta, z);
    k_sem<<<dim3(NSEMBLK), 256, 0, stream>>>(z, W1T, b1, W2, partial);
    k_beta<<<1, 256, 0, stream>>>(partial, betab, (float*)d_out + (size_t)N_NODES * 128);
    k_combine<<<dim3((N_NODES * 16 + 255) / 256), 256, 0, stream>>>(z, betab, (float*)d_out);
}

// Round 15
// 249.838 us; speedup vs baseline: 1.2398x; 1.0520x over previous
//
#include <hip/hip_runtime.h>
#include <hip/hip_bf16.h>

#define N_NODES 50000
#define N_EDGES 600000
#define NMETA   3
#define LTOT (NMETA * N_NODES)          // 150000
#define SPAN_SHIFT 9
#define NBUCK 98                         // ceil(50000 / 512)
#define BCAP 8192
#define NCHUNK 147                       // ceil(600000 / 4096)
#define NABLK 782                        // ceil(50000 / 64)
#define NSLOT (NMETA * NBUCK * BCAP)     // 2408448
#define NSEMBLK ((LTOT / 16 + 3) / 4)    // 2344
#define PREPX_BLKS 800
#define LOG2E 1.4426950408889634f

typedef unsigned short u16;
typedef short bf16x8 __attribute__((ext_vector_type(8)));
typedef float f32x4 __attribute__((ext_vector_type(4)));

__device__ __forceinline__ float bf2f(u16 v) {
    union { unsigned int u; float f; } x; x.u = ((unsigned int)v) << 16; return x.f;
}
__device__ __forceinline__ float u2f(unsigned int u) {
    union { unsigned int u; float f; } x; x.u = u; return x.f;
}
__device__ __forceinline__ u16 f2bf(float f) {
    return __hip_bfloat16_raw(__float2bfloat16(f)).x;
}

#if __has_builtin(__builtin_amdgcn_fdot2_f32_bf16)
#define HAS_DOT2 1
typedef __bf16 bf16x2v __attribute__((ext_vector_type(2)));
__device__ __forceinline__ float dot2bf(unsigned hp, unsigned ep, float acc) {
    return __builtin_amdgcn_fdot2_f32_bf16(
        __builtin_bit_cast(bf16x2v, hp), __builtin_bit_cast(bf16x2v, ep), acc, false);
}
#else
#define HAS_DOT2 0
#endif

// ---- build1: csrA (0..440) || prep_w (441..696) || prep_x (697..) ----
__global__ __launch_bounds__(256) void k_build1(
    const int* __restrict__ ei, int* __restrict__ gcnt,
    unsigned* __restrict__ pairs,
    const float* __restrict__ W, const float* __restrict__ W1,
    u16* __restrict__ WT, u16* __restrict__ W1T,
    const float* __restrict__ x, u16* __restrict__ xb)
{
    const int bid = blockIdx.x;
    const int t = threadIdx.x;
    if (bid >= NMETA * NCHUNK + 256) {
        // ---- prep_x: x f32 -> bf16, grid-stride ----
        const int stride = PREPX_BLKS * 256;
        for (int i = (bid - (NMETA * NCHUNK + 256)) * 256 + t; i < N_NODES * 32; i += stride) {
            float4 v = ((const float4*)x)[i];
            ushort4 o;
            o.x = f2bf(v.x); o.y = f2bf(v.y); o.z = f2bf(v.z); o.w = f2bf(v.w);
            ((ushort4*)xb)[i] = o;
        }
        return;
    }
    if (bid >= NMETA * NCHUNK) {
        int idx = (bid - NMETA * NCHUNK) * 256 + t;
        if (idx < NMETA * 16384) {
            int m = idx >> 14, r = idx & 16383;
            int col = r >> 7, k = r & 127;
            WT[idx] = f2bf(W[(m << 14) + k * 128 + col]);
        } else {
            int r = idx - NMETA * 16384;
            int col = r >> 7, k = r & 127;
            W1T[r] = f2bf(W1[k * 128 + col]);
        }
        return;
    }
    const int m = bid / NCHUNK;
    const int e0 = (bid % NCHUNK) * 4096;
    __shared__ int cnt[NBUCK];
    __shared__ int gbase[NBUCK];
    if (t < NBUCK) cnt[t] = 0;
    __syncthreads();
    const int* srcp = ei + (size_t)m * 2 * N_EDGES;
    const int* dstp = srcp + N_EDGES;
    int sa[16], da[16], sl[16];
    #pragma unroll
    for (int j = 0; j < 16; ++j) {
        int e = e0 + j * 256 + t;
        if (e < N_EDGES) {
            int s = srcp[e], d = dstp[e];
            if ((unsigned)s >= N_NODES) s = 0;
            if ((unsigned)d >= N_NODES) d = 0;
            sa[j] = s; da[j] = d;
            sl[j] = atomicAdd(&cnt[d >> SPAN_SHIFT], 1);
        } else sl[j] = -1;
    }
    __syncthreads();
    if (t < NBUCK) gbase[t] = atomicAdd(&gcnt[(m * NBUCK + t) * 16], cnt[t]);
    __syncthreads();
    #pragma unroll
    for (int j = 0; j < 16; ++j) {
        if (sl[j] < 0) continue;
        int b = da[j] >> SPAN_SHIFT;
        int pos = gbase[b] + sl[j];
        if (pos < BCAP)
            pairs[(size_t)(m * NBUCK + b) * BCAP + pos] =
                ((unsigned)(da[j] & 511) << 23) | (unsigned)(sa[j] * 128);
    }
}

// ---- build2: csrB (0..293) || gemm_h+alpha (rest, reads bf16 xb) ----
__global__ __launch_bounds__(256) void k_build2(
    const int* __restrict__ gcnt, const unsigned* __restrict__ pairs,
    int* __restrict__ row_start, int* __restrict__ row_end, int* __restrict__ eidx,
    int* __restrict__ ptot,
    const u16* __restrict__ xb, const u16* __restrict__ WT,
    const float* __restrict__ att_src, const float* __restrict__ att_dst,
    u16* __restrict__ h, float* __restrict__ alpha_s, float* __restrict__ alpha_d)
{
    const int bid = blockIdx.x;
    const int t = threadIdx.x;
    if (bid < NMETA * NBUCK) {
        const int m = bid / NBUCK, b = bid % NBUCK;
        __shared__ int cnt[512];
        __shared__ int off[512];
        __shared__ int wsum[4];
        int nb = gcnt[(m * NBUCK + b) * 16]; if (nb > BCAP) nb = BCAP;
        const int base = (m * NBUCK + b) * BCAP;
        cnt[t] = 0; cnt[t + 256] = 0;
        __syncthreads();
        for (int e = t; e < nb; e += 256) {
            int dl = (int)(pairs[(size_t)base + e] >> 23);
            atomicAdd(&cnt[dl], 1);
        }
        __syncthreads();
        int c0 = cnt[2 * t], c1 = cnt[2 * t + 1];
        int v0p = (c0 + 3) & ~3, v1p = (c1 + 3) & ~3;
        int s = v0p + v1p;
        int lane = t & 63, wv = t >> 6;
        int incl = s;
        #pragma unroll
        for (int o = 1; o < 64; o <<= 1) {
            int u = __shfl_up(incl, o);
            if (lane >= o) incl += u;
        }
        if (lane == 63) wsum[wv] = incl;
        __syncthreads();
        int woff = 0;
        for (int i = 0; i < wv; ++i) woff += wsum[i];
        int ex = woff + incl - s;
        off[2 * t] = ex;
        off[2 * t + 1] = ex + v0p;
        if (t == 255) {
            int tot = ex + v0p + v1p;
            ptot[m * NBUCK + b] = tot < BCAP ? tot : BCAP;
        }
        for (int q = ex + c0; q < ex + v0p && q < BCAP; ++q) eidx[base + q] = 0;
        for (int q = ex + v0p + c1; q < ex + v0p + v1p && q < BCAP; ++q) eidx[base + q] = 0;
        __syncthreads();
        const int node0 = b << SPAN_SHIFT;
        for (int i = t; i < 512; i += 256) {
            int n = node0 + i;
            if (n < N_NODES) {
                int st = base + off[i];
                row_start[m * N_NODES + n] = st;
                row_end[m * N_NODES + n]   = st + cnt[i];
            }
        }
        __syncthreads();
        for (int e = t; e < nb; e += 256) {
            unsigned pv = pairs[(size_t)base + e];
            int dl = (int)(pv >> 23);
            int pos = atomicAdd(&off[dl], 1);
            if (pos >= BCAP) continue;
            eidx[base + pos] = (int)pv;             // packed dl<<23 | src*128
        }
        return;
    }
    // ---- gemm_h + fused alphas (pre-scaled by LOG2E), bf16 A-fragments ----
    const int g = bid - NMETA * NBUCK;
    const int bx = g % NABLK, m = g / NABLK;
    const int wv = t >> 6, lane = t & 63;
    const int row0 = (bx * 4 + wv) * 16;
    if (row0 >= N_NODES) return;
    const int lhi = lane >> 4, llo = lane & 15;
    const u16* xrow = xb + (size_t)(row0 + llo) * 128 + lhi * 8;
    bf16x8 a[4];
    #pragma unroll
    for (int ks = 0; ks < 4; ++ks) a[ks] = *(const bf16x8*)(xrow + ks * 32);
    const u16* wbase = WT + (size_t)m * 16384 + (size_t)llo * 128 + lhi * 8;
    u16* hm = h + ((size_t)m * N_NODES + row0) * 128;
    float sp[4][4], dp[4][4];
    #pragma unroll
    for (int i = 0; i < 4; ++i)
        #pragma unroll
        for (int r = 0; r < 4; ++r) { sp[i][r] = 0.f; dp[i][r] = 0.f; }
    #pragma unroll
    for (int cf = 0; cf < 8; ++cf) {
        f32x4 acc = {0.f, 0.f, 0.f, 0.f};
        const u16* wp = wbase + cf * 16 * 128;
        #pragma unroll
        for (int ks = 0; ks < 4; ++ks) {
            bf16x8 bb = *(const bf16x8*)(wp + ks * 32);
            acc = __builtin_amdgcn_mfma_f32_16x16x32_bf16(a[ks], bb, acc, 0, 0, 0);
        }
        const int col = cf * 16 + llo;
        const int hh = cf >> 1;
        const float as = att_src[m * 128 + col];
        const float adv = att_dst[m * 128 + col];
        #pragma unroll
        for (int r = 0; r < 4; ++r) {
            hm[(size_t)(lhi * 4 + r) * 128 + col] = f2bf(acc[r]);
            sp[hh][r] += acc[r] * as;
            dp[hh][r] += acc[r] * adv;
        }
    }
    #pragma unroll
    for (int o = 1; o <= 8; o <<= 1) {
        #pragma unroll
        for (int i = 0; i < 4; ++i)
            #pragma unroll
            for (int r = 0; r < 4; ++r) {
                sp[i][r] += __shfl_xor(sp[i][r], o);
                dp[i][r] += __shfl_xor(dp[i][r], o);
            }
    }
    if (llo == 0) {
        #pragma unroll
        for (int r = 0; r < 4; ++r) {
            int n = row0 + lhi * 4 + r;
            f32x4 vs = {sp[0][r] * LOG2E, sp[1][r] * LOG2E, sp[2][r] * LOG2E, sp[3][r] * LOG2E};
            f32x4 vd = {dp[0][r] * LOG2E, dp[1][r] * LOG2E, dp[2][r] * LOG2E, dp[3][r] * LOG2E};
            *(f32x4*)(alpha_s + ((size_t)m * N_NODES + n) * 4) = vs;
            *(f32x4*)(alpha_d + ((size_t)m * N_NODES + n) * 4) = vd;
        }
    }
}

// ---- k_ew: grid-stride per-slot edge weights (transposed ew layout); eidx read-only ----
__global__ __launch_bounds__(256) void k_ew(
    const int* __restrict__ ptot, const int* __restrict__ eidx,
    const float* __restrict__ alpha_s, const float* __restrict__ alpha_d,
    u16* __restrict__ ew)
{
    for (int sidx = blockIdx.x * 256 + threadIdx.x; sidx < NSLOT; sidx += gridDim.x * 256) {
        const int bucket = sidx >> 13;              // / BCAP
        const int i = sidx & (BCAP - 1);
        if (i >= ptot[bucket]) continue;
        const int m = bucket / NBUCK, b = bucket % NBUCK;
        const int node0 = b << SPAN_SHIFT;
        int v = eidx[sidx];
        int src128 = v & 0x7FFFFF;
        int dl = (unsigned)v >> 23;
        const float* as_m = alpha_s + (size_t)m * N_NODES * 4;
        const float* ad_m = alpha_d + (size_t)m * N_NODES * 4;
        f32x4 as4 = *(const f32x4*)(as_m + (src128 >> 5));
        f32x4 ad4 = *(const f32x4*)(ad_m + (size_t)(node0 + dl) * 4);
        u16* ewp = ew + (size_t)(sidx >> 2) * 16 + (sidx & 3);
        #pragma unroll
        for (int k = 0; k < 4; ++k) {
            float pre = as4[k] + ad4[k];
            pre = fmaxf(pre, 0.2f * pre);
            ewp[k * 4] = f2bf(exp2f(pre));
        }
    }
}

// ---- K2: gather (x8 unroll, packed eidx unpacked inline, dot2) + softmax + LN + ELU ----
__global__ __launch_bounds__(256) void k_gather(
    const int* __restrict__ row_start, const int* __restrict__ row_end,
    const int* __restrict__ eidx, const u16* __restrict__ ew,
    const float* __restrict__ alpha_s, const float* __restrict__ alpha_d,
    const u16* __restrict__ h,
    const float* __restrict__ bias, const float* __restrict__ gamma,
    const float* __restrict__ lbeta,
    u16* __restrict__ z)                 // [N, M, 128] bf16
{
    long long w = ((long long)blockIdx.x * blockDim.x + threadIdx.x) >> 6;
    if (w >= (long long)LTOT) return;
    int m = (int)(w / N_NODES), n = (int)(w % N_NODES);
    int lane = threadIdx.x & 63, hh = lane >> 4;
    const char* h_m = (const char*)(h + (size_t)m * N_NODES * 128);
    const char* ewb = (const char*)ew;
    const int lb = lane * 4;
    const float* as_m = alpha_s + (size_t)m * N_NODES * 4;
    const float* ad_m = alpha_d + (size_t)m * N_NODES * 4;
    float pre = as_m[n * 4 + hh] + ad_m[n * 4 + hh];
    pre = fmaxf(pre, 0.2f * pre);
    float ev = exp2f(pre);
    float esum = ev;
    unsigned hv = *(const unsigned*)(h_m + (size_t)n * 256 + lb);
    float acc0 = ev * u2f(hv << 16), acc1 = ev * u2f(hv & 0xffff0000u);
    int p = row_start[m * N_NODES + n];            // 4-aligned
    const int end = row_end[m * N_NODES + n];
    for (; p + 7 < end; p += 8) {
        int4 vA = *(const int4*)(eidx + p);
        int4 vB = *(const int4*)(eidx + p + 4);
        uint2 ewA = *(const uint2*)(ewb + (size_t)(p + hh) * 8);
        uint2 ewB = *(const uint2*)(ewb + (size_t)(p + 4 + hh) * 8);
        unsigned h1 = *(const unsigned*)(h_m + ((vA.x & 0x7FFFFF) << 1) + lb);
        unsigned h2 = *(const unsigned*)(h_m + ((vA.y & 0x7FFFFF) << 1) + lb);
        unsigned h3 = *(const unsigned*)(h_m + ((vA.z & 0x7FFFFF) << 1) + lb);
        unsigned h4 = *(const unsigned*)(h_m + ((vA.w & 0x7FFFFF) << 1) + lb);
        unsigned h5 = *(const unsigned*)(h_m + ((vB.x & 0x7FFFFF) << 1) + lb);
        unsigned h6 = *(const unsigned*)(h_m + ((vB.y & 0x7FFFFF) << 1) + lb);
        unsigned h7 = *(const unsigned*)(h_m + ((vB.z & 0x7FFFFF) << 1) + lb);
        unsigned h8 = *(const unsigned*)(h_m + ((vB.w & 0x7FFFFF) << 1) + lb);
#if HAS_DOT2
        unsigned lo12 = __builtin_amdgcn_perm(h2, h1, 0x05040100u);
        unsigned hi12 = __builtin_amdgcn_perm(h2, h1, 0x07060302u);
        unsigned lo34 = __builtin_amdgcn_perm(h4, h3, 0x05040100u);
        unsigned hi34 = __builtin_amdgcn_perm(h4, h3, 0x07060302u);
        unsigned lo56 = __builtin_amdgcn_perm(h6, h5, 0x05040100u);
        unsigned hi56 = __builtin_amdgcn_perm(h6, h5, 0x07060302u);
        unsigned lo78 = __builtin_amdgcn_perm(h8, h7, 0x05040100u);
        unsigned hi78 = __builtin_amdgcn_perm(h8, h7, 0x07060302u);
        acc0 = dot2bf(lo12, ewA.x, acc0);
        acc1 = dot2bf(hi12, ewA.x, acc1);
        acc0 = dot2bf(lo34, ewA.y, acc0);
        acc1 = dot2bf(hi34, ewA.y, acc1);
        acc0 = dot2bf(lo56, ewB.x, acc0);
        acc1 = dot2bf(hi56, ewB.x, acc1);
        acc0 = dot2bf(lo78, ewB.y, acc0);
        acc1 = dot2bf(hi78, ewB.y, acc1);
        esum = dot2bf(0x3F803F80u, ewA.x, esum);
        esum = dot2bf(0x3F803F80u, ewA.y, esum);
        esum = dot2bf(0x3F803F80u, ewB.x, esum);
        esum = dot2bf(0x3F803F80u, ewB.y, esum);
#else
        float e1 = u2f(ewA.x << 16), e2 = u2f(ewA.x & 0xffff0000u);
        float e3 = u2f(ewA.y << 16), e4 = u2f(ewA.y & 0xffff0000u);
        float e5 = u2f(ewB.x << 16), e6 = u2f(ewB.x & 0xffff0000u);
        float e7 = u2f(ewB.y << 16), e8 = u2f(ewB.y & 0xffff0000u);
        esum += ((e1 + e2) + (e3 + e4)) + ((e5 + e6) + (e7 + e8));
        acc0 += e1 * u2f(h1 << 16) + e2 * u2f(h2 << 16)
              + e3 * u2f(h3 << 16) + e4 * u2f(h4 << 16)
              + e5 * u2f(h5 << 16) + e6 * u2f(h6 << 16)
              + e7 * u2f(h7 << 16) + e8 * u2f(h8 << 16);
        acc1 += e1 * u2f(h1 & 0xffff0000u) + e2 * u2f(h2 & 0xffff0000u)
              + e3 * u2f(h3 & 0xffff0000u) + e4 * u2f(h4 & 0xffff0000u)
              + e5 * u2f(h5 & 0xffff0000u) + e6 * u2f(h6 & 0xffff0000u)
              + e7 * u2f(h7 & 0xffff0000u) + e8 * u2f(h8 & 0xffff0000u);
#endif
    }
    for (; p + 3 < end; p += 4) {
        int4 vA = *(const int4*)(eidx + p);
        uint2 ewv = *(const uint2*)(ewb + (size_t)(p + hh) * 8);
        unsigned h1 = *(const unsigned*)(h_m + ((vA.x & 0x7FFFFF) << 1) + lb);
        unsigned h2 = *(const unsigned*)(h_m + ((vA.y & 0x7FFFFF) << 1) + lb);
        unsigned h3 = *(const unsigned*)(h_m + ((vA.z & 0x7FFFFF) << 1) + lb);
        unsigned h4 = *(const unsigned*)(h_m + ((vA.w & 0x7FFFFF) << 1) + lb);
#if HAS_DOT2
        unsigned lo12 = __builtin_amdgcn_perm(h2, h1, 0x05040100u);
        unsigned hi12 = __builtin_amdgcn_perm(h2, h1, 0x07060302u);
        unsigned lo34 = __builtin_amdgcn_perm(h4, h3, 0x05040100u);
        unsigned hi34 = __builtin_amdgcn_perm(h4, h3, 0x07060302u);
        acc0 = dot2bf(lo12, ewv.x, acc0);
        acc1 = dot2bf(hi12, ewv.x, acc1);
        acc0 = dot2bf(lo34, ewv.y, acc0);
        acc1 = dot2bf(hi34, ewv.y, acc1);
        esum = dot2bf(0x3F803F80u, ewv.x, esum);
        esum = dot2bf(0x3F803F80u, ewv.y, esum);
#else
        float e1 = u2f(ewv.x << 16), e2 = u2f(ewv.x & 0xffff0000u);
        float e3 = u2f(ewv.y << 16), e4 = u2f(ewv.y & 0xffff0000u);
        esum += (e1 + e2) + (e3 + e4);
        acc0 += e1 * u2f(h1 << 16) + e2 * u2f(h2 << 16)
              + e3 * u2f(h3 << 16) + e4 * u2f(h4 << 16);
        acc1 += e1 * u2f(h1 & 0xffff0000u) + e2 * u2f(h2 & 0xffff0000u)
              + e3 * u2f(h3 & 0xffff0000u) + e4 * u2f(h4 & 0xffff0000u);
#endif
    }
    for (; p < end; ++p) {
        int v = eidx[p];
        float e1 = bf2f(*(const u16*)(ewb + (size_t)((p & ~3) + hh) * 8 + (p & 3) * 2));
        unsigned h1 = *(const unsigned*)(h_m + ((v & 0x7FFFFF) << 1) + lb);
        esum += e1;
        acc0 += e1 * u2f(h1 << 16);
        acc1 += e1 * u2f(h1 & 0xffff0000u);
    }
    float rinv = 1.f / (esum + 1e-16f);
    float v0 = acc0 * rinv + bias[m * 128 + lane * 2];
    float v1 = acc1 * rinv + bias[m * 128 + lane * 2 + 1];
    float s1 = v0 + v1, s2 = v0 * v0 + v1 * v1;
    #pragma unroll
    for (int o = 32; o >= 1; o >>= 1) { s1 += __shfl_xor(s1, o); s2 += __shfl_xor(s2, o); }
    float mu = s1 * (1.f / 128.f);
    float var = s2 * (1.f / 128.f) - mu * mu;
    float rs = rsqrtf(var + 1e-5f);
    float o0 = (v0 - mu) * rs * gamma[lane * 2]     + lbeta[lane * 2];
    float o1 = (v1 - mu) * rs * gamma[lane * 2 + 1] + lbeta[lane * 2 + 1];
    o0 = o0 > 0.f ? o0 : (__expf(o0) - 1.f);
    o1 = o1 > 0.f ? o1 : (__expf(o1) - 1.f);
    ushort2 outv; outv.x = f2bf(o0); outv.y = f2bf(o1);
    *(ushort2*)(z + ((size_t)n * NMETA + m) * 128 + lane * 2) = outv;
}

// ---- K4: semantic scores via MFMA; per-block partial -> own cache line ----
__global__ __launch_bounds__(256) void k_sem(
    const u16* __restrict__ z, const u16* __restrict__ W1T,
    const float* __restrict__ b1, const float* __restrict__ W2,
    float4* __restrict__ partial)
{
    __shared__ float part[NMETA];
    const int t = threadIdx.x;
    if (t < NMETA) part[t] = 0.f;
    __syncthreads();
    const int wv = t >> 6, lane = t & 63;
    const int row0 = (blockIdx.x * 4 + wv) * 16;
    if (row0 < LTOT) {
        const int lhi = lane >> 4, llo = lane & 15;
        const u16* zrow = z + (size_t)(row0 + llo) * 128 + lhi * 8;
        bf16x8 a[4];
        #pragma unroll
        for (int ks = 0; ks < 4; ++ks) a[ks] = *(const bf16x8*)(zrow + ks * 32);
        const u16* wb = W1T + (size_t)llo * 128 + lhi * 8;
        float rowacc[4] = {0.f, 0.f, 0.f, 0.f};
        #pragma unroll
        for (int cf = 0; cf < 8; ++cf) {
            f32x4 acc = {0.f, 0.f, 0.f, 0.f};
            const u16* wp = wb + cf * 16 * 128;
            #pragma unroll
            for (int ks = 0; ks < 4; ++ks) {
                bf16x8 bb = *(const bf16x8*)(wp + ks * 32);
                acc = __builtin_amdgcn_mfma_f32_16x16x32_bf16(a[ks], bb, acc, 0, 0, 0);
            }
            int col = cf * 16 + llo;
            float b1v = b1[col], w2v = W2[col];
            #pragma unroll
            for (int r = 0; r < 4; ++r) {
                float targ = acc[r] + b1v;
                float tv = 1.f - 2.f / (exp2f(targ * (2.f * LOG2E)) + 1.f);  // tanh
                rowacc[r] += tv * w2v;
            }
        }
        #pragma unroll
        for (int o = 1; o <= 8; o <<= 1) {
            #pragma unroll
            for (int r = 0; r < 4; ++r) rowacc[r] += __shfl_xor(rowacc[r], o);
        }
        if (llo == 0) {
            #pragma unroll
            for (int r = 0; r < 4; ++r)
                atomicAdd(&part[(row0 + lhi * 4 + r) % NMETA], rowacc[r]);
        }
    }
    __syncthreads();
    if (t == 0)
        partial[blockIdx.x] = make_float4(part[0], part[1], part[2], 0.f);
}

// ---- K5: reduce partials + softmax ----
__global__ __launch_bounds__(256) void k_beta(
    const float4* __restrict__ partial, float* __restrict__ betab,
    float* __restrict__ attout)
{
    const int t = threadIdx.x;
    float s0 = 0.f, s1 = 0.f, s2 = 0.f;
    for (int i = t; i < NSEMBLK; i += 256) {
        float4 v = partial[i];
        s0 += v.x; s1 += v.y; s2 += v.z;
    }
    #pragma unroll
    for (int o = 32; o >= 1; o >>= 1) {
        s0 += __shfl_xor(s0, o);
        s1 += __shfl_xor(s1, o);
        s2 += __shfl_xor(s2, o);
    }
    __shared__ float wsum[3][4];
    int lane = t & 63, wv = t >> 6;
    if (lane == 0) { wsum[0][wv] = s0; wsum[1][wv] = s1; wsum[2][wv] = s2; }
    __syncthreads();
    if (t == 0) {
        float w0 = (wsum[0][0] + wsum[0][1] + wsum[0][2] + wsum[0][3]) * (1.f / N_NODES);
        float w1 = (wsum[1][0] + wsum[1][1] + wsum[1][2] + wsum[1][3]) * (1.f / N_NODES);
        float w2 = (wsum[2][0] + wsum[2][1] + wsum[2][2] + wsum[2][3]) * (1.f / N_NODES);
        float mx = fmaxf(w0, fmaxf(w1, w2));
        float e0 = __expf(w0 - mx), e1 = __expf(w1 - mx), e2 = __expf(w2 - mx);
        float s = 1.f / (e0 + e1 + e2);
        float b0 = e0 * s, b1v = e1 * s, b2 = e2 * s;
        betab[0] = b0; betab[1] = b1v; betab[2] = b2;
        attout[0] = b0; attout[1] = b1v; attout[2] = b2;
    }
}

// ---- K6: out_emb = sum_m beta[m] * z[:,m,:] (8 cols / thread) ----
__global__ __launch_bounds__(256) void k_combine(
    const u16* __restrict__ z, const float* __restrict__ betab,
    float* __restrict__ out)
{
    int idx = blockIdx.x * blockDim.x + threadIdx.x;   // N*16 tasks
    if (idx >= N_NODES * 16) return;
    int n = idx >> 4, c8 = (idx & 15) * 8;
    float b0 = betab[0], b1 = betab[1], b2 = betab[2];
    const u16* zp = z + (size_t)n * 384 + c8;
    uint4 a0 = *(const uint4*)(zp);
    uint4 a1 = *(const uint4*)(zp + 128);
    uint4 a2 = *(const uint4*)(zp + 256);
    const unsigned* p0 = (const unsigned*)&a0;
    const unsigned* p1 = (const unsigned*)&a1;
    const unsigned* p2 = (const unsigned*)&a2;
    float o[8];
    #pragma unroll
    for (int j = 0; j < 4; ++j) {
        o[2 * j]     = b0 * u2f(p0[j] << 16) + b1 * u2f(p1[j] << 16) + b2 * u2f(p2[j] << 16);
        o[2 * j + 1] = b0 * u2f(p0[j] & 0xffff0000u) + b1 * u2f(p1[j] & 0xffff0000u)
                     + b2 * u2f(p2[j] & 0xffff0000u);
    }
    float* op = out + (size_t)n * 128 + c8;
    *(float4*)(op)     = make_float4(o[0], o[1], o[2], o[3]);
    *(float4*)(op + 4) = make_float4(o[4], o[5], o[6], o[7]);
}

extern "C" void kernel_launch(void* const* d_in, const int* in_sizes, int n_in,
                              void* d_out, int out_size, void* d_ws, size_t ws_size,
                              hipStream_t stream) {
    const float* x       = (const float*)d_in[0];
    const int*   ei      = (const int*)d_in[1];
    const float* W       = (const float*)d_in[2];
    const float* att_src = (const float*)d_in[3];
    const float* att_dst = (const float*)d_in[4];
    const float* bias    = (const float*)d_in[5];
    const float* gamma   = (const float*)d_in[6];
    const float* lbeta   = (const float*)d_in[7];
    const float* W1      = (const float*)d_in[8];
    const float* b1      = (const float*)d_in[9];
    const float* W2      = (const float*)d_in[10];

    char* ws = (char*)d_ws;
    size_t off = 0;
    int* gcnt    = (int*)(ws + off);  off += sizeof(int) * 512 * 16;     // padded: 1 line / bucket
    int* ptot    = (int*)(ws + off);  off += sizeof(int) * 512;
    float* betab = (float*)(ws + off); off += 64;
    const size_t zero_bytes = off;
    off = (off + 255) & ~(size_t)255;
    float4* partial = (float4*)(ws + off); off += sizeof(float4) * (NSEMBLK + 8);
    int* row_start = (int*)(ws + off); off += sizeof(int) * 150016;
    int* row_end   = (int*)(ws + off); off += sizeof(int) * 150016;
    u16* h      = (u16*)(ws + off);    off += sizeof(u16) * (size_t)NMETA * N_NODES * 128;
    float* alpha_s = (float*)(ws + off); off += sizeof(float) * (size_t)LTOT * 4;
    float* alpha_d = (float*)(ws + off); off += sizeof(float) * (size_t)LTOT * 4;
    u16* WT     = (u16*)(ws + off);    off += sizeof(u16) * (size_t)NMETA * 128 * 128;
    u16* W1T    = (u16*)(ws + off);    off += sizeof(u16) * (size_t)128 * 128;
    int* eidx   = (int*)(ws + off);    off += sizeof(int) * (size_t)NSLOT;          // 9.6 MB
    u16* ew     = (u16*)(ws + off);    off += sizeof(u16) * (size_t)NSLOT * 4;      // 19.3 MB
    // union region (disjoint lifetimes): pairs+xb (build1->build2), z (gather->end)
    unsigned* pairs = (unsigned*)(ws + off);                             // 9.6 MB
    u16* xb = (u16*)(ws + off + sizeof(unsigned) * (size_t)NSLOT);       // 12.8 MB
    u16* z  = (u16*)(ws + off);
    off += sizeof(u16) * (size_t)N_NODES * NMETA * 128;                  // 38.4 MB (covers both)
    if (ws_size < off) return;  // ~112 MB needed; loud failure if undersized

    hipMemsetAsync(d_ws, 0, zero_bytes, stream);

    // build1: csrA (441) || prep_w (256) || prep_x (800)
    k_build1<<<dim3(NMETA * NCHUNK + 256 + PREPX_BLKS), 256, 0, stream>>>(
        ei, gcnt, pairs, W, W1, WT, W1T, x, xb);
    // build2: csrB (294) || gemm_h+alpha (2346)
    k_build2<<<dim3(NMETA * NBUCK + NABLK * NMETA), 256, 0, stream>>>(
        gcnt, pairs, row_start, row_end, eidx, ptot,
        xb, WT, att_src, att_dst, h, alpha_s, alpha_d);
    k_ew<<<dim3(2048), 256, 0, stream>>>(ptot, eidx, alpha_s, alpha_d, ew);
    k_gather<<<dim3((LTOT + 3) / 4), 256, 0, stream>>>(row_start, row_end, eidx, ew,
                                                       alpha_s, alpha_d, h,
                                                       bias, gamma, lbeta, z);
    k_sem<<<dim3(NSEMBLK), 256, 0, stream>>>(z, W1T, b1, W2, partial);
    k_beta<<<1, 256, 0, stream>>>(partial, betab, (float*)d_out + (size_t)N_NODES * 128);
    k_combine<<<dim3((N_NODES * 16 + 255) / 256), 256, 0, stream>>>(z, betab, (float*)d_out);
}